// Round 9
// baseline (773.263 us; speedup 1.0000x reference)
//
#include <hip/hip_runtime.h>

#define B_ 16
#define N_ 2048
#define IN_ 12
#define H_ 64
#define K_ 16

// Skewed LDS index: row-major [r][k] tiles, stride 68 + 4-float skew per 4 rows.
#define IDX(r, k) ((r) * 68 + ((r) >> 2) * 4 + (k))

// ---------------------------------------------------------------------------
// Kernel A: emb = relu(x@W1+b1)@W2+b2 (one wave per row); sref = 1/max(||e||,eps)
// (byte-identical to round 4 — passing arithmetic, do not modify)
// ---------------------------------------------------------------------------
__global__ __launch_bounds__(256) void emb_kernel(
    const float* __restrict__ x, const float* __restrict__ W1,
    const float* __restrict__ b1, const float* __restrict__ W2,
    const float* __restrict__ b2, float* __restrict__ emb_out,
    float* __restrict__ sref) {
  const int lane = threadIdx.x & 63;
  const int wid = threadIdx.x >> 6;
  const long long row = (long long)blockIdx.x * 4 + wid;  // 0..32767

  const float* xr = x + row * IN_;
  float xv[IN_];
#pragma unroll
  for (int k = 0; k < IN_; ++k) xv[k] = xr[k];

  float acc = b1[lane];
#pragma unroll
  for (int k = 0; k < IN_; ++k) acc += xv[k] * W1[k * H_ + lane];
  float h = fmaxf(acc, 0.f);

  float e = b2[lane];
#pragma unroll
  for (int j = 0; j < H_; ++j) {
    float hj = __shfl(h, j, 64);
    e += hj * W2[j * H_ + lane];
  }

  float ss = e * e;
#pragma unroll
  for (int off = 32; off; off >>= 1) ss += __shfl_xor(ss, off, 64);
  float s = 1.0f / fmaxf(sqrtf(ss), 1e-12f);

  emb_out[row * H_ + lane] = e;
  if (lane == 0) sref[row] = s;
}

// ---------------------------------------------------------------------------
// Phase 1: fused sim + partial top-16 over one column half. Round-7 GEMM
// and merge structure verbatim (4 rows x 8 cols per thread, 64-row stripe);
// only the column range (8 tiles of this half) and the epilogue differ:
// instead of writing the dense stripe, each row's sorted 16-key rank list
// is stored into that row's adj region (cols [half*32, half*32+32) floats).
// Sim values bit-identical to rounds 4/7.
// ---------------------------------------------------------------------------
__device__ __forceinline__ unsigned mono32(float v) {
  unsigned u = __float_as_uint(v);
  return u ^ ((unsigned)((int)u >> 31) | 0x80000000u);
}

#define MKKEY(A4, SJ, J)                                                      \
  ((((unsigned long long)mono32(                                              \
        ((A4).x + (A4).y + (A4).z + (A4).w) * (SJ)))                          \
    << 32) |                                                                  \
   (unsigned)(N_ - 1 - (J)))

#define MERGE_ROW(KR)                                                         \
  {                                                                           \
    unsigned cons = 0u;                                                       \
    unsigned long long cmax = 0ull;                                           \
    _Pragma("unroll") for (int q = 0; q < 8; ++q)                             \
        if (ck[q] > cmax) cmax = ck[q];                                       \
    unsigned long long tau = __shfl(KR, 15, 16);                              \
    while (((__ballot(cmax > tau) >> gsh) & 0xFFFFull) != 0ull) {             \
      unsigned long long bk = cmax;                                           \
      _Pragma("unroll") for (int off = 8; off; off >>= 1) {                   \
        const unsigned long long ok = __shfl_xor(bk, off, 16);                \
        if (ok > bk) bk = ok;                                                 \
      }                                                                       \
      const int pos =                                                         \
          __popc((unsigned)((__ballot(KR > bk) >> gsh) & 0xFFFFull));         \
      const unsigned long long up = __shfl_up(KR, 1, 16);                     \
      KR = (tx == pos) ? bk : (tx > pos ? up : KR);                           \
      if (cmax == bk) {                                                       \
        unsigned long long nm = 0ull;                                         \
        _Pragma("unroll") for (int q = 0; q < 8; ++q) {                       \
          if (ck[q] == bk) cons |= (1u << q);                                 \
          if (!((cons >> q) & 1u) && ck[q] > nm) nm = ck[q];                  \
        }                                                                     \
        cmax = nm;                                                            \
      }                                                                       \
      tau = __shfl(KR, 15, 16);                                               \
    }                                                                         \
  }

#define FMA_ROW(ACC, AV)                                                      \
  _Pragma("unroll") for (int q = 0; q < 8; ++q) {                             \
    ACC[q].x += (AV).x * bv[q].x;                                             \
    ACC[q].y += (AV).y * bv[q].y;                                             \
    ACC[q].z += (AV).z * bv[q].z;                                             \
    ACC[q].w += (AV).w * bv[q].w;                                             \
  }

__global__ __launch_bounds__(256) void fused_kernel(
    const float* __restrict__ emb, const float* __restrict__ sref,
    float* __restrict__ adj) {
  __shared__ float As[4408];  // 64 rows, pre-scaled  (IDX(63,63)+1)
  __shared__ float Bs[8824];  // 128 rows, raw        (IDX(127,63)+1)

  const int t = threadIdx.x;
  const int b = blockIdx.x >> 6;           // 64 blocks per batch
  const int rem = blockIdx.x & 63;
  const int i0 = (rem >> 1) * 64;          // stripe base row
  const int ch = rem & 1;                  // column half (0: 0..1023, 1: 1024..2047)

  const float* Eb = emb + (size_t)b * N_ * H_;
  const float* srb = sref + b * N_;

  // ---- stage A-stripe once: 64 rows, pre-scaled by s_i ----
  {
    const int r = t >> 2;            // 0..63
    const int k0 = (t & 3) * 16;
    const float sA = srb[i0 + r];
    const float* src = Eb + (size_t)(i0 + r) * H_ + k0;
#pragma unroll
    for (int i = 0; i < 4; ++i) {
      const float4 v = *(const float4*)(src + i * 4);
      float4 w;
      w.x = v.x * sA; w.y = v.y * sA; w.z = v.z * sA; w.w = v.w * sA;
      *(float4*)&As[IDX(r, k0 + i * 4)] = w;
    }
  }

  const int tx = t & 15, ty = t >> 4;
  const int r0 = ty * 4;                 // group's first row (0..60)
  const int gsh = (t & 63) & 0x30;       // group base lane within wave

  unsigned long long kr0 = 0ull, kr1 = 0ull, kr2 = 0ull, kr3 = 0ull;

  int bof[8];
#pragma unroll
  for (int q = 0; q < 4; ++q) {
    bof[q] = IDX(tx * 4 + q, 0);
    bof[q + 4] = IDX(64 + tx * 4 + q, 0);
  }
  const int aof0 = IDX(r0 + 0, 0), aof1 = IDX(r0 + 1, 0);
  const int aof2 = IDX(r0 + 2, 0), aof3 = IDX(r0 + 3, 0);

  for (int tj = ch * 8; tj < ch * 8 + 8; ++tj) {
    __syncthreads();  // prior tile's Bs reads done (covers A-stage on first)
    // ---- stage B-tile: 128 rows, raw ----
    {
      const int r = t >> 1;            // 0..127
      const int k0 = (t & 1) * 32;
      const float* src = Eb + (size_t)(tj * 128 + r) * H_ + k0;
#pragma unroll
      for (int i = 0; i < 8; ++i) {
        const float4 v = *(const float4*)(src + i * 4);
        *(float4*)&Bs[IDX(r, k0 + i * 4)] = v;
      }
    }
    __syncthreads();

    float4 a0[8], a1[8], a2[8], a3[8];
#pragma unroll
    for (int q = 0; q < 8; ++q) {
      a0[q] = make_float4(0.f, 0.f, 0.f, 0.f);
      a1[q] = make_float4(0.f, 0.f, 0.f, 0.f);
      a2[q] = make_float4(0.f, 0.f, 0.f, 0.f);
      a3[q] = make_float4(0.f, 0.f, 0.f, 0.f);
    }

#pragma unroll 4
    for (int dg = 0; dg < 16; ++dg) {
      const float4 av0 = *(const float4*)&As[aof0 + dg * 4];
      const float4 av1 = *(const float4*)&As[aof1 + dg * 4];
      const float4 av2 = *(const float4*)&As[aof2 + dg * 4];
      const float4 av3 = *(const float4*)&As[aof3 + dg * 4];
      float4 bv[8];
#pragma unroll
      for (int q = 0; q < 8; ++q) bv[q] = *(const float4*)&Bs[bof[q] + dg * 4];
      FMA_ROW(a0, av0);
      FMA_ROW(a1, av1);
      FMA_ROW(a2, av2);
      FMA_ROW(a3, av3);
    }

    // ---- epilogue + merge (per row; cols jb..jb+3 and jb+64..jb+67) ----
    const int jb = tj * 128 + tx * 4;
    const float4 sj0 = *(const float4*)(srb + jb);
    const float4 sj1 = *(const float4*)(srb + jb + 64);

    unsigned long long ck[8];
    ck[0] = MKKEY(a0[0], sj0.x, jb + 0);
    ck[1] = MKKEY(a0[1], sj0.y, jb + 1);
    ck[2] = MKKEY(a0[2], sj0.z, jb + 2);
    ck[3] = MKKEY(a0[3], sj0.w, jb + 3);
    ck[4] = MKKEY(a0[4], sj1.x, jb + 64);
    ck[5] = MKKEY(a0[5], sj1.y, jb + 65);
    ck[6] = MKKEY(a0[6], sj1.z, jb + 66);
    ck[7] = MKKEY(a0[7], sj1.w, jb + 67);
    MERGE_ROW(kr0);

    ck[0] = MKKEY(a1[0], sj0.x, jb + 0);
    ck[1] = MKKEY(a1[1], sj0.y, jb + 1);
    ck[2] = MKKEY(a1[2], sj0.z, jb + 2);
    ck[3] = MKKEY(a1[3], sj0.w, jb + 3);
    ck[4] = MKKEY(a1[4], sj1.x, jb + 64);
    ck[5] = MKKEY(a1[5], sj1.y, jb + 65);
    ck[6] = MKKEY(a1[6], sj1.z, jb + 66);
    ck[7] = MKKEY(a1[7], sj1.w, jb + 67);
    MERGE_ROW(kr1);

    ck[0] = MKKEY(a2[0], sj0.x, jb + 0);
    ck[1] = MKKEY(a2[1], sj0.y, jb + 1);
    ck[2] = MKKEY(a2[2], sj0.z, jb + 2);
    ck[3] = MKKEY(a2[3], sj0.w, jb + 3);
    ck[4] = MKKEY(a2[4], sj1.x, jb + 64);
    ck[5] = MKKEY(a2[5], sj1.y, jb + 65);
    ck[6] = MKKEY(a2[6], sj1.z, jb + 66);
    ck[7] = MKKEY(a2[7], sj1.w, jb + 67);
    MERGE_ROW(kr2);

    ck[0] = MKKEY(a3[0], sj0.x, jb + 0);
    ck[1] = MKKEY(a3[1], sj0.y, jb + 1);
    ck[2] = MKKEY(a3[2], sj0.z, jb + 2);
    ck[3] = MKKEY(a3[3], sj0.w, jb + 3);
    ck[4] = MKKEY(a3[4], sj1.x, jb + 64);
    ck[5] = MKKEY(a3[5], sj1.y, jb + 65);
    ck[6] = MKKEY(a3[6], sj1.z, jb + 66);
    ck[7] = MKKEY(a3[7], sj1.w, jb + 67);
    MERGE_ROW(kr3);
  }

  // ---- write this half's sorted 16-key list into the row's adj region ----
  // row r keys live at float cols [ch*32, ch*32+32)  == u64 slots [ch*16+tx]
  {
    float* stripe = adj + ((size_t)b * N_ + i0) * N_;
    unsigned long long* kp0 = (unsigned long long*)(stripe + (size_t)(r0 + 0) * N_);
    unsigned long long* kp1 = (unsigned long long*)(stripe + (size_t)(r0 + 1) * N_);
    unsigned long long* kp2 = (unsigned long long*)(stripe + (size_t)(r0 + 2) * N_);
    unsigned long long* kp3 = (unsigned long long*)(stripe + (size_t)(r0 + 3) * N_);
    const int slot = ch * 16 + tx;
    kp0[slot] = kr0;
    kp1[slot] = kr1;
    kp2[slot] = kr2;
    kp3[slot] = kr3;
  }
}

// ---------------------------------------------------------------------------
// Phase 2: per row, merge the two sorted 16-key lists (bitonic, width-32),
// zero the row, scatter the 16 winners (values recovered exactly from keys).
// One 32-lane half-wave per row; 8 rows per 256-thread block.
// ---------------------------------------------------------------------------
__global__ __launch_bounds__(256) void merge_kernel(float* __restrict__ adj) {
  const int t = threadIdx.x;
  const int wid = t >> 6;
  const int rh = (t >> 5) & 1;   // row within wave
  const int sub = t & 31;
  const size_t row = (size_t)blockIdx.x * 8 + wid * 2 + rh;
  float* rp = adj + row * N_;

  // listA (desc) in lanes 0..15; listB reversed (asc) in lanes 16..31
  // -> [A desc | B asc] is bitonic.
  const int src = (sub < 16) ? sub : (47 - sub);
  unsigned long long key = ((const unsigned long long*)rp)[src];

  // bitonic merge, descending, width 32
#pragma unroll
  for (int d = 16; d; d >>= 1) {
    const unsigned long long ok = __shfl_xor(key, d, 32);
    const bool keepmax = (sub & d) == 0;
    const unsigned long long mx = key > ok ? key : ok;
    const unsigned long long mn = key > ok ? ok : key;
    key = keepmax ? mx : mn;
  }

  // zero the row (keys were loaded before these stores; same-address hazard
  // ordering within a lane is compiler/waitcnt-handled — round-6-proven)
  const float4 z4 = make_float4(0.f, 0.f, 0.f, 0.f);
#pragma unroll
  for (int m2 = 0; m2 < 16; ++m2)
    ((float4*)rp)[m2 * 32 + sub] = z4;
  __syncthreads();  // drains vmcnt -> zeros land before the scatter

  if (sub < K_) {
    const int j = N_ - 1 - (int)(key & 0xFFFFFFFFull);
    const unsigned m = (unsigned)(key >> 32);
    const unsigned u = (m & 0x80000000u) ? (m ^ 0x80000000u) : ~m;
    rp[j] = __uint_as_float(u);
  }
}

extern "C" void kernel_launch(void* const* d_in, const int* in_sizes, int n_in,
                              void* d_out, int out_size, void* d_ws, size_t ws_size,
                              hipStream_t stream) {
  const float* x  = (const float*)d_in[0];
  const float* W1 = (const float*)d_in[1];
  const float* b1 = (const float*)d_in[2];
  const float* W2 = (const float*)d_in[3];
  const float* b2 = (const float*)d_in[4];

  float* adj  = (float*)d_out;                              // B*N*N
  float* embo = (float*)d_out + (size_t)B_ * N_ * N_;       // B*N*H
  float* sref = (float*)d_ws;                               // B*N floats

  emb_kernel<<<(B_ * N_) / 4, 256, 0, stream>>>(x, W1, b1, W2, b2, embo, sref);
  fused_kernel<<<B_ * 64, 256, 0, stream>>>(embo, sref, adj);     // 32 stripes x 2 halves
  merge_kernel<<<(B_ * N_) / 8, 256, 0, stream>>>(adj);
}

// Round 10
// 312.195 us; speedup vs baseline: 2.4769x; 2.4769x over previous
//
#include <hip/hip_runtime.h>

#define B_ 16
#define N_ 2048
#define IN_ 12
#define H_ 64
#define K_ 16

// Skewed LDS index: row-major [r][k] tiles, stride 68 + 4-float skew per 4 rows.
#define IDX(r, k) ((r) * 68 + ((r) >> 2) * 4 + (k))

// ---------------------------------------------------------------------------
// Kernel A: emb = relu(x@W1+b1)@W2+b2 (one wave per row); sref = 1/max(||e||,eps)
// (byte-identical to round 4 — passing arithmetic, do not modify)
// ---------------------------------------------------------------------------
__global__ __launch_bounds__(256) void emb_kernel(
    const float* __restrict__ x, const float* __restrict__ W1,
    const float* __restrict__ b1, const float* __restrict__ W2,
    const float* __restrict__ b2, float* __restrict__ emb_out,
    float* __restrict__ sref) {
  const int lane = threadIdx.x & 63;
  const int wid = threadIdx.x >> 6;
  const long long row = (long long)blockIdx.x * 4 + wid;  // 0..32767

  const float* xr = x + row * IN_;
  float xv[IN_];
#pragma unroll
  for (int k = 0; k < IN_; ++k) xv[k] = xr[k];

  float acc = b1[lane];
#pragma unroll
  for (int k = 0; k < IN_; ++k) acc += xv[k] * W1[k * H_ + lane];
  float h = fmaxf(acc, 0.f);

  float e = b2[lane];
#pragma unroll
  for (int j = 0; j < H_; ++j) {
    float hj = __shfl(h, j, 64);
    e += hj * W2[j * H_ + lane];
  }

  float ss = e * e;
#pragma unroll
  for (int off = 32; off; off >>= 1) ss += __shfl_xor(ss, off, 64);
  float s = 1.0f / fmaxf(sqrtf(ss), 1e-12f);

  emb_out[row * H_ + lane] = e;
  if (lane == 0) sref[row] = s;
}

// ---------------------------------------------------------------------------
// Kernel B: sim tile GEMM, retiled 64x64 per block, 4x4 outputs/thread.
// acc shrinks 128->64 VGPRs -> 4 waves/SIMD (launch_bounds(256,4)).
// Per-output arithmetic EXPRESSION-IDENTICAL to round 6 (passing):
//   A staged as fl(e*s_i), B raw; float4 of 4 FMA chains over dg=0..15
//   ascending; epilogue (x+y+z+w)*s_j.
// ---------------------------------------------------------------------------
__global__ __launch_bounds__(256, 4) void sim_kernel(
    const float* __restrict__ emb, const float* __restrict__ sref,
    float* __restrict__ adj) {
  __shared__ float As[4408];  // 64 rows, pre-scaled (IDX(63,63)+1)
  __shared__ float Bs[4408];  // 64 rows, raw

  const int t = threadIdx.x;
  const int nTj = N_ / 64;                 // 32
  const int tilesPerB = (N_ / 64) * nTj;   // 1024
  const int b = blockIdx.x / tilesPerB;
  const int tl = blockIdx.x % tilesPerB;
  const int ti = tl / nTj, tj = tl % nTj;

  const float* Eb = emb + (size_t)b * N_ * H_;
  const float* srb = sref + b * N_;

  // ---- stage A-tile: rows ti*64..+64, pre-scaled by s_i ----
  {
    const int r = t >> 2;              // 0..63
    const int k0 = (t & 3) * 16;
    const float sA = srb[ti * 64 + r];
    const float* src = Eb + (size_t)(ti * 64 + r) * H_ + k0;
#pragma unroll
    for (int i = 0; i < 4; ++i) {
      const float4 v = *(const float4*)(src + i * 4);
      float4 w;
      w.x = v.x * sA; w.y = v.y * sA; w.z = v.z * sA; w.w = v.w * sA;
      *(float4*)&As[IDX(r, k0 + i * 4)] = w;
    }
  }
  // ---- stage B-tile: rows tj*64..+64, raw ----
  {
    const int r = t >> 2;
    const int k0 = (t & 3) * 16;
    const float* src = Eb + (size_t)(tj * 64 + r) * H_ + k0;
#pragma unroll
    for (int i = 0; i < 4; ++i) {
      const float4 v = *(const float4*)(src + i * 4);
      *(float4*)&Bs[IDX(r, k0 + i * 4)] = v;
    }
  }
  __syncthreads();

  const int tx = t & 15, ty = t >> 4;
  const int r0 = ty * 4, c0 = tx * 4;

  float4 acc[4][4];
#pragma unroll
  for (int rr = 0; rr < 4; ++rr)
#pragma unroll
    for (int cc = 0; cc < 4; ++cc) acc[rr][cc] = make_float4(0.f, 0.f, 0.f, 0.f);

  int aoff[4], boff[4];
#pragma unroll
  for (int rr = 0; rr < 4; ++rr) aoff[rr] = IDX(r0 + rr, 0);
#pragma unroll
  for (int cc = 0; cc < 4; ++cc) boff[cc] = IDX(c0 + cc, 0);

#pragma unroll 4
  for (int dg = 0; dg < 16; ++dg) {
    float4 av[4], bv[4];
#pragma unroll
    for (int rr = 0; rr < 4; ++rr) av[rr] = *(const float4*)&As[aoff[rr] + dg * 4];
#pragma unroll
    for (int cc = 0; cc < 4; ++cc) bv[cc] = *(const float4*)&Bs[boff[cc] + dg * 4];
#pragma unroll
    for (int rr = 0; rr < 4; ++rr)
#pragma unroll
      for (int cc = 0; cc < 4; ++cc) {
        acc[rr][cc].x += av[rr].x * bv[cc].x;
        acc[rr][cc].y += av[rr].y * bv[cc].y;
        acc[rr][cc].z += av[rr].z * bv[cc].z;
        acc[rr][cc].w += av[rr].w * bv[cc].w;
      }
  }

  // ---- epilogue: (x+y+z+w) * s_j, store ----
  const float4 sjv = *(const float4*)(srb + tj * 64 + c0);
  float* out = adj + (size_t)b * N_ * N_ + (size_t)(ti * 64 + r0) * N_ + tj * 64 + c0;
#pragma unroll
  for (int rr = 0; rr < 4; ++rr) {
    float4 o;
    o.x = (acc[rr][0].x + acc[rr][0].y + acc[rr][0].z + acc[rr][0].w) * sjv.x;
    o.y = (acc[rr][1].x + acc[rr][1].y + acc[rr][1].z + acc[rr][1].w) * sjv.y;
    o.z = (acc[rr][2].x + acc[rr][2].y + acc[rr][2].z + acc[rr][2].w) * sjv.z;
    o.w = (acc[rr][3].x + acc[rr][3].y + acc[rr][3].z + acc[rr][3].w) * sjv.w;
    *(float4*)(out + (size_t)rr * N_) = o;
  }
}

// ---------------------------------------------------------------------------
// Kernel C: in-place top-16 per row (round-6 structure). u64 key =
// mono(v)<<32 | (N-1-j). NEW: butterfly runs on the 32-bit value word only
// (6 single-dword shuffles instead of 6 u64 shuffles); unique-max fast path
// broadcasts the winner's full key from its lane (provably the u64 max);
// exact u64 butterfly fallback on value ties (wave-uniform branch).
// Selection semantics identical.
// ---------------------------------------------------------------------------
__device__ __forceinline__ unsigned mono32(float v) {
  unsigned u = __float_as_uint(v);
  return u ^ ((unsigned)((int)u >> 31) | 0x80000000u);
}

#define GKEY_BUILD(G, DST)                                                  \
  {                                                                         \
    unsigned long long k2 = 0ull;                                           \
    _Pragma("unroll") for (int c = 0; c < 4; ++c) {                         \
      const int s2 = ((G) << 2) | c;                                        \
      if (!((taken >> s2) & 1u)) {                                          \
        const int jj = ((G) << 8) + (lane << 2) + c;                        \
        const unsigned long long key =                                      \
            ((unsigned long long)mono32(vals[s2]) << 32) |                  \
            (unsigned)(N_ - 1 - jj);                                        \
        if (key > k2) k2 = key;                                             \
      }                                                                     \
    }                                                                       \
    DST = k2;                                                               \
  }

__global__ __launch_bounds__(256) void topk_kernel(float* __restrict__ adj) {
  const int lane = threadIdx.x & 63;
  const int wid = threadIdx.x >> 6;
  const size_t row = (size_t)blockIdx.x * 4 + wid;  // 0..32767
  float* rp = adj + row * N_;

  // element j = g*256 + lane*4 + c lives in vals[g*4+c]
  float vals[32];
#pragma unroll
  for (int g = 0; g < 8; ++g) {
    const float4 v = *((const float4*)rp + g * 64 + lane);
    vals[g * 4 + 0] = v.x; vals[g * 4 + 1] = v.y;
    vals[g * 4 + 2] = v.z; vals[g * 4 + 3] = v.w;
  }

  unsigned taken = 0u;
  unsigned long long gk0, gk1, gk2, gk3, gk4, gk5, gk6, gk7;
  GKEY_BUILD(0, gk0); GKEY_BUILD(1, gk1); GKEY_BUILD(2, gk2); GKEY_BUILD(3, gk3);
  GKEY_BUILD(4, gk4); GKEY_BUILD(5, gk5); GKEY_BUILD(6, gk6); GKEY_BUILD(7, gk7);

#define LK_REFRESH()                                                        \
  lk = gk0;                                                                 \
  if (gk1 > lk) lk = gk1;                                                   \
  if (gk2 > lk) lk = gk2;                                                   \
  if (gk3 > lk) lk = gk3;                                                   \
  if (gk4 > lk) lk = gk4;                                                   \
  if (gk5 > lk) lk = gk5;                                                   \
  if (gk6 > lk) lk = gk6;                                                   \
  if (gk7 > lk) lk = gk7

  unsigned long long lk;
  LK_REFRESH();

  for (int it = 0; it < K_; ++it) {
    // 32-bit value butterfly (cheap); winner's u64 key fetched after.
    const unsigned lv32 = (unsigned)(lk >> 32);
    unsigned bv32 = lv32;
#pragma unroll
    for (int off = 32; off; off >>= 1) {
      const unsigned ov = __shfl_xor(bv32, off, 64);
      if (ov > bv32) bv32 = ov;
    }
    const unsigned long long mask = __ballot(lv32 == bv32);
    unsigned long long bk;
    if (__popcll(mask) == 1) {
      // unique max value -> that lane's full key IS the u64 max
      const int srcl = (int)(__ffsll((long long)mask) - 1);
      bk = __shfl(lk, srcl, 64);
    } else {
      // value tie across lanes (rare, wave-uniform): exact u64 butterfly
      bk = lk;
#pragma unroll
      for (int off = 32; off; off >>= 1) {
        const unsigned long long ok = __shfl_xor(bk, off, 64);
        if (ok > bk) bk = ok;
      }
    }

    const int j = N_ - 1 - (int)(bk & 0xFFFFFFFFull);
    const bool own = ((j >> 2) & 63) == lane;
    const int g = j >> 8;
    if (own) taken |= 1u << ((g << 2) | (j & 3));
    switch (g) {  // wave-uniform branch; static register indexing per arm
      case 0: if (own) GKEY_BUILD(0, gk0); break;
      case 1: if (own) GKEY_BUILD(1, gk1); break;
      case 2: if (own) GKEY_BUILD(2, gk2); break;
      case 3: if (own) GKEY_BUILD(3, gk3); break;
      case 4: if (own) GKEY_BUILD(4, gk4); break;
      case 5: if (own) GKEY_BUILD(5, gk5); break;
      case 6: if (own) GKEY_BUILD(6, gk6); break;
      default: if (own) GKEY_BUILD(7, gk7); break;
    }
    LK_REFRESH();
  }

  // merged write: winners keep value, everything else zero
#pragma unroll
  for (int g2 = 0; g2 < 8; ++g2) {
    float4 o;
    o.x = ((taken >> (g2 * 4 + 0)) & 1u) ? vals[g2 * 4 + 0] : 0.f;
    o.y = ((taken >> (g2 * 4 + 1)) & 1u) ? vals[g2 * 4 + 1] : 0.f;
    o.z = ((taken >> (g2 * 4 + 2)) & 1u) ? vals[g2 * 4 + 2] : 0.f;
    o.w = ((taken >> (g2 * 4 + 3)) & 1u) ? vals[g2 * 4 + 3] : 0.f;
    *((float4*)rp + g2 * 64 + lane) = o;
  }
}

extern "C" void kernel_launch(void* const* d_in, const int* in_sizes, int n_in,
                              void* d_out, int out_size, void* d_ws, size_t ws_size,
                              hipStream_t stream) {
  const float* x  = (const float*)d_in[0];
  const float* W1 = (const float*)d_in[1];
  const float* b1 = (const float*)d_in[2];
  const float* W2 = (const float*)d_in[3];
  const float* b2 = (const float*)d_in[4];

  float* adj  = (float*)d_out;                              // B*N*N
  float* embo = (float*)d_out + (size_t)B_ * N_ * N_;       // B*N*H
  float* sref = (float*)d_ws;                               // B*N floats

  emb_kernel<<<(B_ * N_) / 4, 256, 0, stream>>>(x, W1, b1, W2, b2, embo, sref);
  sim_kernel<<<B_ * (N_ / 64) * (N_ / 64), 256, 0, stream>>>(embo, sref, adj);
  topk_kernel<<<(B_ * N_) / 4, 256, 0, stream>>>(adj);
}

// Round 11
// 245.199 us; speedup vs baseline: 3.1536x; 1.2732x over previous
//
#include <hip/hip_runtime.h>

#define B_ 16
#define N_ 2048
#define IN_ 12
#define H_ 64
#define K_ 16

// Skewed LDS index: row-major [r][k] tiles, stride 68 + 4-float skew per 4 rows.
#define IDX(r, k) ((r) * 68 + ((r) >> 2) * 4 + (k))

// ---------------------------------------------------------------------------
// Kernel A: emb = relu(x@W1+b1)@W2+b2 (one wave per row); sref = 1/max(||e||,eps)
// (byte-identical to round 4 — passing arithmetic, do not modify)
// ---------------------------------------------------------------------------
__global__ __launch_bounds__(256) void emb_kernel(
    const float* __restrict__ x, const float* __restrict__ W1,
    const float* __restrict__ b1, const float* __restrict__ W2,
    const float* __restrict__ b2, float* __restrict__ emb_out,
    float* __restrict__ sref) {
  const int lane = threadIdx.x & 63;
  const int wid = threadIdx.x >> 6;
  const long long row = (long long)blockIdx.x * 4 + wid;  // 0..32767

  const float* xr = x + row * IN_;
  float xv[IN_];
#pragma unroll
  for (int k = 0; k < IN_; ++k) xv[k] = xr[k];

  float acc = b1[lane];
#pragma unroll
  for (int k = 0; k < IN_; ++k) acc += xv[k] * W1[k * H_ + lane];
  float h = fmaxf(acc, 0.f);

  float e = b2[lane];
#pragma unroll
  for (int j = 0; j < H_; ++j) {
    float hj = __shfl(h, j, 64);
    e += hj * W2[j * H_ + lane];
  }

  float ss = e * e;
#pragma unroll
  for (int off = 32; off; off >>= 1) ss += __shfl_xor(ss, off, 64);
  float s = 1.0f / fmaxf(sqrtf(ss), 1e-12f);

  emb_out[row * H_ + lane] = e;
  if (lane == 0) sref[row] = s;
}

// ---------------------------------------------------------------------------
// Kernel B: sim tile GEMM, 128x64 per block, 8x4 outputs/thread.
// (byte-identical to round 6 — best measured, passing arithmetic)
// ---------------------------------------------------------------------------
__global__ __launch_bounds__(256) void sim_kernel(
    const float* __restrict__ emb, const float* __restrict__ sref,
    float* __restrict__ adj) {
  __shared__ float As[8824];  // IDX(127,63)+1
  __shared__ float Bs[4408];  // IDX(63,63)+1

  const int t = threadIdx.x;
  const int nTj = N_ / 64;                 // 32
  const int tilesPerB = (N_ / 128) * nTj;  // 512
  const int b = blockIdx.x / tilesPerB;
  const int tl = blockIdx.x % tilesPerB;
  const int ti = tl / nTj, tj = tl % nTj;

  const float* Eb = emb + (size_t)b * N_ * H_;
  const float* srb = sref + b * N_;

  // ---- stage A-tile: rows ti*128..+128, pre-scaled by s_i ----
  {
    const int r = t >> 1;              // 0..127
    const int k0 = (t & 1) * 32;       // 0 or 32
    const float sA = srb[ti * 128 + r];
    const float* src = Eb + (size_t)(ti * 128 + r) * H_ + k0;
#pragma unroll
    for (int i = 0; i < 8; ++i) {
      const float4 v = *(const float4*)(src + i * 4);
      float4 w;
      w.x = v.x * sA; w.y = v.y * sA; w.z = v.z * sA; w.w = v.w * sA;
      *(float4*)&As[IDX(r, k0 + i * 4)] = w;
    }
  }
  // ---- stage B-tile: rows tj*64..+64, raw e_j ----
  {
    const int r = t >> 2;              // 0..63
    const int k0 = (t & 3) * 16;
    const float* src = Eb + (size_t)(tj * 64 + r) * H_ + k0;
#pragma unroll
    for (int i = 0; i < 4; ++i) {
      const float4 v = *(const float4*)(src + i * 4);
      *(float4*)&Bs[IDX(r, k0 + i * 4)] = v;
    }
  }
  __syncthreads();

  const int tx = t & 15, ty = t >> 4;
  const int r0 = ty * 8, c0 = tx * 4;

  float4 acc[8][4];
#pragma unroll
  for (int rr = 0; rr < 8; ++rr)
#pragma unroll
    for (int cc = 0; cc < 4; ++cc) acc[rr][cc] = make_float4(0.f, 0.f, 0.f, 0.f);

  int aoff[8], boff[4];
#pragma unroll
  for (int rr = 0; rr < 8; ++rr) aoff[rr] = IDX(r0 + rr, 0);
#pragma unroll
  for (int cc = 0; cc < 4; ++cc) boff[cc] = IDX(c0 + cc, 0);

#pragma unroll 4
  for (int dg = 0; dg < 16; ++dg) {
    float4 av[8], bv[4];
#pragma unroll
    for (int rr = 0; rr < 8; ++rr) av[rr] = *(const float4*)&As[aoff[rr] + dg * 4];
#pragma unroll
    for (int cc = 0; cc < 4; ++cc) bv[cc] = *(const float4*)&Bs[boff[cc] + dg * 4];
#pragma unroll
    for (int rr = 0; rr < 8; ++rr)
#pragma unroll
      for (int cc = 0; cc < 4; ++cc) {
        acc[rr][cc].x += av[rr].x * bv[cc].x;
        acc[rr][cc].y += av[rr].y * bv[cc].y;
        acc[rr][cc].z += av[rr].z * bv[cc].z;
        acc[rr][cc].w += av[rr].w * bv[cc].w;
      }
  }

  // ---- epilogue: (x+y+z+w) * s_j, store ----
  const float4 sjv = *(const float4*)(srb + tj * 64 + c0);
  float* out = adj + (size_t)b * N_ * N_ + (size_t)(ti * 128 + r0) * N_ + tj * 64 + c0;
#pragma unroll
  for (int rr = 0; rr < 8; ++rr) {
    float4 o;
    o.x = (acc[rr][0].x + acc[rr][0].y + acc[rr][0].z + acc[rr][0].w) * sjv.x;
    o.y = (acc[rr][1].x + acc[rr][1].y + acc[rr][1].z + acc[rr][1].w) * sjv.y;
    o.z = (acc[rr][2].x + acc[rr][2].y + acc[rr][2].z + acc[rr][2].w) * sjv.z;
    o.w = (acc[rr][3].x + acc[rr][3].y + acc[rr][3].z + acc[rr][3].w) * sjv.w;
    *(float4*)(out + (size_t)rr * N_) = o;
  }
}

// ---------------------------------------------------------------------------
// Kernel C: in-place top-16 per row. One wave per row, row in registers.
// u64 key = mono(v)<<32 | (N-1-j): total order, value desc / index asc
// (lax.top_k semantics) — comparator unchanged from passing rounds.
// NEW: per-lane top-2 cache. Initial pass caches each lane's best + 2nd-best
// key; a lane's first loss promotes #2 (3 ops); a second loss (rare) takes
// an execz-skipped exact rescan with the taken mask. Butterfly runs on the
// 32-bit value word; unique-max broadcasts the winner's full key; exact u64
// butterfly fallback on cross-lane value ties.
// ---------------------------------------------------------------------------
__device__ __forceinline__ unsigned mono32(float v) {
  unsigned u = __float_as_uint(v);
  return u ^ ((unsigned)((int)u >> 31) | 0x80000000u);
}

__global__ __launch_bounds__(256) void topk_kernel(float* __restrict__ adj) {
  const int lane = threadIdx.x & 63;
  const int wid = threadIdx.x >> 6;
  const size_t row = (size_t)blockIdx.x * 4 + wid;  // 0..32767
  float* rp = adj + row * N_;

  // element j = (s>>2)*256 + lane*4 + (s&3) lives in vals[s]
  float vals[32];
#pragma unroll
  for (int g = 0; g < 8; ++g) {
    const float4 v = *((const float4*)rp + g * 64 + lane);
    vals[g * 4 + 0] = v.x; vals[g * 4 + 1] = v.y;
    vals[g * 4 + 2] = v.z; vals[g * 4 + 3] = v.w;
  }

  // ---- per-lane top-2 (ascending slot scan, strict > => lowest j on ties)
  float v1 = vals[0], v2 = -2.f;
  int s1 = 0, sB = 0;
#pragma unroll
  for (int s = 1; s < 32; ++s) {
    const float v = vals[s];
    if (v > v1) { v2 = v1; sB = s1; v1 = v; s1 = s; }
    else if (v > v2) { v2 = v; sB = s; }
  }
  // pack keys: j(slot) = ((slot>>2)<<8) + (lane<<2) + (slot&3)
#define SLOT2J(S) ((((S) >> 2) << 8) + (lane << 2) + ((S)&3))
  unsigned long long lk =
      ((unsigned long long)mono32(v1) << 32) | (unsigned)(N_ - 1 - SLOT2J(s1));
  unsigned long long k2 =
      ((unsigned long long)mono32(v2) << 32) | (unsigned)(N_ - 1 - SLOT2J(sB));

  unsigned taken = 0u;
  int nlost = 0;

  for (int it = 0; it < K_; ++it) {
    // 32-bit value butterfly; unique-max fast path
    const unsigned lv = (unsigned)(lk >> 32);
    unsigned bv = lv;
#pragma unroll
    for (int off = 32; off; off >>= 1) {
      const unsigned ov = __shfl_xor(bv, off, 64);
      if (ov > bv) bv = ov;
    }
    const unsigned long long mask = __ballot(lv == bv);
    unsigned long long bk;
    if (__popcll(mask) == 1) {
      const int srcl = (int)(__ffsll((long long)mask) - 1);
      bk = __shfl(lk, srcl, 64);
    } else {
      bk = lk;  // cross-lane value tie (rare, wave-uniform): exact u64
#pragma unroll
      for (int off = 32; off; off >>= 1) {
        const unsigned long long ok = __shfl_xor(bk, off, 64);
        if (ok > bk) bk = ok;
      }
    }

    const int j = N_ - 1 - (int)(bk & 0xFFFFFFFFull);
    const bool own = ((j >> 2) & 63) == lane;
    if (own) {
      taken |= 1u << (((j >> 8) << 2) | (j & 3));
      if (it < K_ - 1) {
        if (nlost == 0) {
          lk = k2;        // promote cached #2 (exact: #2 unseen by removals)
          nlost = 1;
        } else {
          nlost = 2;      // mark: rescan below
        }
      }
    }
    // rare exact rescan (execz-skipped when no lane needs it)
    if (own && nlost == 2) {
      float nv = -2.f; int ns = 0;
#pragma unroll
      for (int s = 0; s < 32; ++s) {
        if (!((taken >> s) & 1u) && vals[s] > nv) { nv = vals[s]; ns = s; }
      }
      lk = ((unsigned long long)mono32(nv) << 32) |
           (unsigned)(N_ - 1 - SLOT2J(ns));
    }
  }

  // merged write: winners keep value, everything else zero
#pragma unroll
  for (int g = 0; g < 8; ++g) {
    float4 o;
    o.x = ((taken >> (g * 4 + 0)) & 1u) ? vals[g * 4 + 0] : 0.f;
    o.y = ((taken >> (g * 4 + 1)) & 1u) ? vals[g * 4 + 1] : 0.f;
    o.z = ((taken >> (g * 4 + 2)) & 1u) ? vals[g * 4 + 2] : 0.f;
    o.w = ((taken >> (g * 4 + 3)) & 1u) ? vals[g * 4 + 3] : 0.f;
    *((float4*)rp + g * 64 + lane) = o;
  }
}

extern "C" void kernel_launch(void* const* d_in, const int* in_sizes, int n_in,
                              void* d_out, int out_size, void* d_ws, size_t ws_size,
                              hipStream_t stream) {
  const float* x  = (const float*)d_in[0];
  const float* W1 = (const float*)d_in[1];
  const float* b1 = (const float*)d_in[2];
  const float* W2 = (const float*)d_in[3];
  const float* b2 = (const float*)d_in[4];

  float* adj  = (float*)d_out;                              // B*N*N
  float* embo = (float*)d_out + (size_t)B_ * N_ * N_;       // B*N*H
  float* sref = (float*)d_ws;                               // B*N floats

  emb_kernel<<<(B_ * N_) / 4, 256, 0, stream>>>(x, W1, b1, W2, b2, embo, sref);
  sim_kernel<<<B_ * (N_ / 128) * (N_ / 64), 256, 0, stream>>>(embo, sref, adj);
  topk_kernel<<<(B_ * N_) / 4, 256, 0, stream>>>(adj);
}